// Round 8
// baseline (147.546 us; speedup 1.0000x reference)
//
#include <hip/hip_runtime.h>
#include <hip/hip_fp16.h>
#include <stdint.h>

// SoftmaxSelfAttention: B=2 H=16 S=2048 D=64, fp32 in/out.
// R12: V to registers, issued FIRST. R11 post-mortem: R6/R7/R11 all ~57-60us
// despite 2x different LDS traffic and 2x occupancy => serialization-bound
// (LDS 42%, VALU 33%, MFMA 35%, HBM 7%: nothing saturated; barrier restarts
// the serial K-read -> QK -> exp2 -> V-read -> PV chain each step).
// Change (single variable): V fragments are lane-addressed and L2-resident
// (R8 proved direct-global V correct; its regression was mi-LAST ordering
// draining vmcnt before QK). Per step: [16 V reg-loads] -> sched_barrier(0)
// -> [K/m GLDS] -> K ds_reads/QK/exp2 -> PV from regs -> barrier. In-order
// vmcnt: PV's wait leaves GLDS in flight; barrier drains only GLDS issued a
// full step ago. Removes V LDS-read burst + V staging. mi stays in LDS.
// LDS 66.5KB -> 36.9KB (epilogue xls needs 36.9KB). No setprio (lockstep).

#define S_LEN   2048
#define DHEAD   64
#define NTILE   16                      // 64-kv tiles per group
#define CEXP    9.0f
#define SCL2E   0.18033688011112042f    // (1/sqrt(64)) * log2(e)
#define L2E     1.4426950408889634f

typedef __attribute__((ext_vector_type(4))) float    f32x4;
typedef __attribute__((ext_vector_type(2))) _Float16 f16x2;
typedef __attribute__((ext_vector_type(4))) _Float16 f16x4;
typedef __attribute__((ext_vector_type(8))) _Float16 f16x8;
typedef __attribute__((ext_vector_type(2))) __fp16   hf16x2;

static __device__ __forceinline__ float exp2_fast(float x) {
#if __has_builtin(__builtin_amdgcn_exp2f)
  return __builtin_amdgcn_exp2f(x);
#else
  float r;
  asm("v_exp_f32 %0, %1" : "=v"(r) : "v"(x));
  return r;
#endif
}

static __device__ __forceinline__ hf16x2 pkh(float a, float b) {
  return __builtin_amdgcn_cvt_pkrtz(a, b);
}
static __device__ __forceinline__ f16x2 h2f(hf16x2 h) {
  union { hf16x2 i; f16x2 o; } u; u.i = h; return u.o;
}

#define GLDS16(g, l)                                                  \
  __builtin_amdgcn_global_load_lds(                                   \
      (const __attribute__((address_space(1))) void*)(g),             \
      (__attribute__((address_space(3))) void*)(l), 16, 0, 0)

// ---------------------------------------------------------------- prep ----
// Blocks [0,2048): K image, chunk c (8 f16) of row kv at rotated pos
// (c+kv)&7; also madd_g[b][kv]. Blocks [2048,6144): V image, granule-major:
// granule (bh,j,g,d) = {V[64j+4g+i][d], i=0..3} at flat (bh<<15|j<<10|g<<6|d).
__global__ __launch_bounds__(256) void prep(
    const float* __restrict__ K, const float* __restrict__ V,
    const float* __restrict__ Mk, _Float16* __restrict__ Kswz,
    _Float16* __restrict__ Vg, float* __restrict__ madd_g) {
  const int gb = blockIdx.x;
  if (gb < 2048) {
    const int idx = gb * 256 + threadIdx.x;   // bh<<14 | kv<<3 | c
    const int c  = idx & 7;
    const int kv = (idx >> 3) & 2047;
    const int bh = idx >> 14;
    const float* src = K + ((size_t)bh * S_LEN + kv) * DHEAD + c * 8;
    float4 a = *(const float4*)(src);
    float4 d = *(const float4*)(src + 4);
    union { f16x2 h[4]; f16x8 v; } r;
    r.h[0] = h2f(pkh(a.x, a.y)); r.h[1] = h2f(pkh(a.z, a.w));
    r.h[2] = h2f(pkh(d.x, d.y)); r.h[3] = h2f(pkh(d.z, d.w));
    *(f16x8*)(Kswz + ((size_t)bh * S_LEN + kv) * DHEAD + ((c + kv) & 7) * 8) = r.v;
    if (idx < 2 * S_LEN)
      madd_g[idx] = -CEXP - (1.0e6f * L2E) * (1.0f - Mk[idx]);
  } else {
    const int idx = (gb - 2048) * 256 + threadIdx.x;  // bh<<15 | j<<10 | g<<6 | d
    const int d  = idx & 63;
    const int g  = (idx >> 6) & 15;
    const int j  = (idx >> 10) & 31;
    const int bh = idx >> 15;
    const float* src = V + ((size_t)bh * S_LEN + j * 64 + g * 4) * DHEAD + d;
    float v0 = src[0], v1 = src[64], v2 = src[128], v3 = src[192];
    union { f16x2 h[2]; f16x4 v; } r;
    r.h[0] = h2f(pkh(v0, v1)); r.h[1] = h2f(pkh(v2, v3));
    *(f16x4*)(Vg + (size_t)idx * 4) = r.v;
  }
}

// ---------------------------------------------------------------- main ----
// 512 threads = 8 waves. Waves 0-3 (group 0): kv [0,1024); waves 4-7
// (group 1): kv [1024,2048). Each wave owns 2 q-strips (w4*16 and +64).
// Per group: double-buffered 64-kv K stream in LDS; V direct global->reg.
// LDS f16 map: K streams [0,16384), m at f16 16384; epilogue reuses smem.
__global__ __launch_bounds__(512)
__attribute__((amdgpu_waves_per_eu(4, 4)))
void attn_ws(
    const float* __restrict__ Q, const _Float16* __restrict__ Kswz,
    const _Float16* __restrict__ Vg, const float* __restrict__ madd_g,
    float* __restrict__ O) {
  __shared__ __align__(16) _Float16 smem[18464];   // 36928 B

  const int tid  = threadIdx.x;       // 0..511
  const int lane = tid & 63;
  const int wave = tid >> 6;          // 0..7
  const int quad = lane >> 4;
  const int x    = lane & 15;
  const int g    = wave >> 2;         // kv half
  const int w4   = wave & 3;
  const int tidg = tid & 255;         // thread id within group

  // grid 512: 16 q-blocks (128 rows) x 32 bh; same-bh blocks share an XCD.
  const int blk  = blockIdx.x;
  const int bh   = (blk & 7) | (((blk >> 3) & 3) << 3);
  const int qblk = blk >> 5;          // 0..15
  const int b    = bh >> 4;

  const size_t base = (size_t)bh * S_LEN * DHEAD;
  const float*    Qb = Q + base;
  const _Float16* Kb = Kswz + base;
  const _Float16* Vb = Vg + base;
  const float*    Mb = madd_g + b * S_LEN;
  float* Ob = O + base;

  // integer LDS offsets (f16 units)
  const int koff = (g * 2) << 12;                              // + cur*4096
  float* const mbase = (float*)(smem + 16384) + (g * 2) * 64;  // + cur*64

  // Q fragments (B-operand of S^T = K Q^T) for two q-strips, pre-scaled.
  const int q0 = qblk * 128 + w4 * 16 + x;
  f16x8 qf[2][2];
#pragma unroll
  for (int u = 0; u < 2; ++u) {
    const float* qp = Qb + (size_t)(q0 + u * 64) * DHEAD + quad * 8;
#pragma unroll
    for (int kb = 0; kb < 2; ++kb) {
      float4 a = *(const float4*)(qp + kb * 32);
      float4 c = *(const float4*)(qp + kb * 32 + 4);
      union { f16x2 h[4]; f16x8 v; } r;
      r.h[0] = h2f(pkh(a.x * SCL2E, a.y * SCL2E));
      r.h[1] = h2f(pkh(a.z * SCL2E, a.w * SCL2E));
      r.h[2] = h2f(pkh(c.x * SCL2E, c.y * SCL2E));
      r.h[3] = h2f(pkh(c.z * SCL2E, c.w * SCL2E));
      qf[u][kb] = r.v;
    }
  }

  // prefetch one 64-kv K tile of this group's stream: 8KB + m 256B.
  auto prefetch = [&](int p, int bi) {
    const size_t off = (size_t)(g * NTILE + p) * 4096;
    const _Float16* ks = Kb + off + tidg * 8;
    _Float16* kd = smem + koff + bi * 4096 + tidg * 8;
    GLDS16(ks,        kd);
    GLDS16(ks + 2048, kd + 2048);
    if (tidg < 16)
      GLDS16(Mb + (g * NTILE + p) * 64 + tidg * 4, mbase + bi * 64 + tidg * 4);
  };

  // per-lane base for direct-global V granules (layout from prep's V image)
  const _Float16* vlane = Vb + 256 * quad + 4 * x;

  f32x4 xacc[2][4];
#pragma unroll
  for (int u = 0; u < 2; ++u)
#pragma unroll
    for (int m = 0; m < 4; ++m) xacc[u][m] = (f32x4){0.f, 0.f, 0.f, 0.f};
  float lsum[2] = {0.0f, 0.0f};
  const hf16x2 one2 = {(__fp16)1.0f, (__fp16)1.0f};

  prefetch(0, 0);
  __syncthreads();

  for (int p = 0; p < NTILE; ++p) {
    const int cur = p & 1;

    // V for this step: straight to registers, issued FIRST (oldest in the
    // vmem queue) so PV's wait leaves the K GLDS prefetch in flight.
    const _Float16* vp = vlane + (size_t)(g * NTILE + p) * 4096;
    f16x4 vf[4][4];
#pragma unroll
    for (int t = 0; t < 4; ++t)
#pragma unroll
      for (int m = 0; m < 4; ++m)
        vf[t][m] = *(const f16x4*)(vp + t * 1024 + m * 64);
    // pin issue order: V loads above, GLDS prefetch below
    __builtin_amdgcn_sched_barrier(0);

    if (p + 1 < NTILE) prefetch(p + 1, cur ^ 1);

    // S^T: A = K rows (rotated chunks), B = Q frags; K/mi shared by u=0,1.
    const _Float16* k0 = smem + koff + cur * 4096 + x * 64 + ((quad + x) & 7) * 8;
    const _Float16* k1 = smem + koff + cur * 4096 + x * 64 + ((quad + 4 + x) & 7) * 8;
    const float*    mp = mbase + cur * 64 + quad * 4;
    f16x4 pf[2][4];
#pragma unroll
    for (int t = 0; t < 4; ++t) {
      f16x8 ka0 = *(const f16x8*)(k0 + t * 1024);
      f16x8 ka1 = *(const f16x8*)(k1 + t * 1024);
      f32x4 mi = *(const f32x4*)(mp + t * 16);   // LDS broadcast read
#pragma unroll
      for (int u = 0; u < 2; ++u) {
        f32x4 st = __builtin_amdgcn_mfma_f32_16x16x32_f16(ka0, qf[u][0], mi, 0, 0, 0);
        st = __builtin_amdgcn_mfma_f32_16x16x32_f16(ka1, qf[u][1], st, 0, 0, 0);
        hf16x2 h0 = pkh(exp2_fast(st.x), exp2_fast(st.y));
        hf16x2 h1 = pkh(exp2_fast(st.z), exp2_fast(st.w));
#if __has_builtin(__builtin_amdgcn_fdot2)
        lsum[u] = __builtin_amdgcn_fdot2(h0, one2, lsum[u], false);
        lsum[u] = __builtin_amdgcn_fdot2(h1, one2, lsum[u], false);
#else
        f16x2 a0 = h2f(h0), a1 = h2f(h1);
        lsum[u] += (float)a0.x + (float)a0.y + (float)a1.x + (float)a1.y;
#endif
        union { f16x2 h[2]; f16x4 v; } r;
        r.h[0] = h2f(h0);
        r.h[1] = h2f(h1);
        pf[u][t] = r.v;
      }
    }
    // X^T += V^T P^T. V granules already in registers; serve both strips.
#pragma unroll
    for (int m = 0; m < 4; ++m) {
      f32x4 x0 = xacc[0][m];
      f32x4 x1 = xacc[1][m];
#pragma unroll
      for (int t = 0; t < 4; ++t) {
        x0 = __builtin_amdgcn_mfma_f32_16x16x16f16(vf[t][m], pf[0][t], x0, 0, 0, 0);
        x1 = __builtin_amdgcn_mfma_f32_16x16x16f16(vf[t][m], pf[1][t], x1, 0, 0, 0);
      }
      xacc[0][m] = x0;
      xacc[1][m] = x1;
    }
    __syncthreads();
  }

  // combine kv-halves: group 1 writes partials to LDS, group 0 reduces.
  // stride 36 floats keeps f32x4 alignment; one-shot epilogue cost.
  float* xls = (float*)smem;
  const int soff = (w4 * 64 + lane) * 36;
  if (g == 1) {
#pragma unroll
    for (int u = 0; u < 2; ++u) {
#pragma unroll
      for (int m = 0; m < 4; ++m)
        *(f32x4*)(xls + soff + (u * 4 + m) * 4) = xacc[u][m];
      xls[soff + 32 + u] = lsum[u];
    }
  }
  __syncthreads();
  if (g == 0) {
#pragma unroll
    for (int u = 0; u < 2; ++u) {
#pragma unroll
      for (int m = 0; m < 4; ++m) {
        f32x4 o = *(const f32x4*)(xls + soff + (u * 4 + m) * 4);
        xacc[u][m].x += o.x; xacc[u][m].y += o.y;
        xacc[u][m].z += o.z; xacc[u][m].w += o.w;
      }
      float l = lsum[u] + xls[soff + 32 + u];
      l += __shfl_xor(l, 16, 64);
      l += __shfl_xor(l, 32, 64);
      const float rl = 1.0f / l;
      float* op = Ob + (size_t)(q0 + u * 64) * DHEAD;
#pragma unroll
      for (int m = 0; m < 4; ++m) {
        float4 o;
        o.x = xacc[u][m].x * rl; o.y = xacc[u][m].y * rl;
        o.z = xacc[u][m].z * rl; o.w = xacc[u][m].w * rl;
        *(float4*)(op + m * 16 + quad * 4) = o;
      }
    }
  }
}

extern "C" void kernel_launch(void* const* d_in, const int* in_sizes, int n_in,
                              void* d_out, int out_size, void* d_ws, size_t ws_size,
                              hipStream_t stream) {
  const float* Q = (const float*)d_in[0];
  const float* K = (const float*)d_in[1];
  const float* V = (const float*)d_in[2];
  const float* M = (const float*)d_in[3];
  float* O = (float*)d_out;

  _Float16* Kswz = (_Float16*)d_ws;
  _Float16* Vg   = Kswz + 4194304;                       // +8 MB
  float*    madd = (float*)((char*)d_ws + 16777216);     // +16 MB
  hipLaunchKernelGGL(prep, dim3(6144), dim3(256), 0, stream, K, V, M, Kswz, Vg, madd);
  hipLaunchKernelGGL(attn_ws, dim3(512), dim3(512), 0, stream, Q, Kswz, Vg, madd, O);
}

// Round 9
// 146.966 us; speedup vs baseline: 1.0039x; 1.0039x over previous
//
#include <hip/hip_runtime.h>
#include <hip/hip_fp16.h>
#include <stdint.h>

// SoftmaxSelfAttention: B=2 H=16 S=2048 D=64, fp32 in/out.
// R13 = R12 with the VGPR-budget trap removed (single variable: LDS size).
// R12 post-mortem: V-to-registers regressed via SPILL, not structure —
// WRITE_SIZE +9.2MB (= 262k threads x ~36B scratch), VGPR_Count=64 while the
// body needs ~110. Mechanism: allocator budgets VGPRs for the occupancy the
// LDS footprint PERMITS (37KB -> 4 blocks/CU -> 8 waves/EU -> 64 VGPRs),
// ignoring that the 512-block grid only ever puts 2 blocks/CU. R11 (66.5KB
// -> 2 blocks -> 128 budget) allocated 56 freely.
// Fix: pad LDS to 57.3KB (>53.3KB) so only 2 blocks/CU fit -> 128-VGPR
// budget -> vf[4][4]+qf+xacc+pf fit without spill. LDS is free (grid gives
// 2 blocks/CU regardless). Everything else byte-identical to R12:
// per step [16 V reg-loads] -> sched_barrier -> [K/m GLDS prefetch] ->
// K ds_reads/QK/exp2 -> PV from regs -> barrier. V off the LDS pipe.

#define S_LEN   2048
#define DHEAD   64
#define NTILE   16                      // 64-kv tiles per group
#define CEXP    9.0f
#define SCL2E   0.18033688011112042f    // (1/sqrt(64)) * log2(e)
#define L2E     1.4426950408889634f

typedef __attribute__((ext_vector_type(4))) float    f32x4;
typedef __attribute__((ext_vector_type(2))) _Float16 f16x2;
typedef __attribute__((ext_vector_type(4))) _Float16 f16x4;
typedef __attribute__((ext_vector_type(8))) _Float16 f16x8;
typedef __attribute__((ext_vector_type(2))) __fp16   hf16x2;

static __device__ __forceinline__ float exp2_fast(float x) {
#if __has_builtin(__builtin_amdgcn_exp2f)
  return __builtin_amdgcn_exp2f(x);
#else
  float r;
  asm("v_exp_f32 %0, %1" : "=v"(r) : "v"(x));
  return r;
#endif
}

static __device__ __forceinline__ hf16x2 pkh(float a, float b) {
  return __builtin_amdgcn_cvt_pkrtz(a, b);
}
static __device__ __forceinline__ f16x2 h2f(hf16x2 h) {
  union { hf16x2 i; f16x2 o; } u; u.i = h; return u.o;
}

#define GLDS16(g, l)                                                  \
  __builtin_amdgcn_global_load_lds(                                   \
      (const __attribute__((address_space(1))) void*)(g),             \
      (__attribute__((address_space(3))) void*)(l), 16, 0, 0)

// ---------------------------------------------------------------- prep ----
// Blocks [0,2048): K image, chunk c (8 f16) of row kv at rotated pos
// (c+kv)&7; also madd_g[b][kv]. Blocks [2048,6144): V image, granule-major:
// granule (bh,j,g,d) = {V[64j+4g+i][d], i=0..3} at flat (bh<<15|j<<10|g<<6|d).
__global__ __launch_bounds__(256) void prep(
    const float* __restrict__ K, const float* __restrict__ V,
    const float* __restrict__ Mk, _Float16* __restrict__ Kswz,
    _Float16* __restrict__ Vg, float* __restrict__ madd_g) {
  const int gb = blockIdx.x;
  if (gb < 2048) {
    const int idx = gb * 256 + threadIdx.x;   // bh<<14 | kv<<3 | c
    const int c  = idx & 7;
    const int kv = (idx >> 3) & 2047;
    const int bh = idx >> 14;
    const float* src = K + ((size_t)bh * S_LEN + kv) * DHEAD + c * 8;
    float4 a = *(const float4*)(src);
    float4 d = *(const float4*)(src + 4);
    union { f16x2 h[4]; f16x8 v; } r;
    r.h[0] = h2f(pkh(a.x, a.y)); r.h[1] = h2f(pkh(a.z, a.w));
    r.h[2] = h2f(pkh(d.x, d.y)); r.h[3] = h2f(pkh(d.z, d.w));
    *(f16x8*)(Kswz + ((size_t)bh * S_LEN + kv) * DHEAD + ((c + kv) & 7) * 8) = r.v;
    if (idx < 2 * S_LEN)
      madd_g[idx] = -CEXP - (1.0e6f * L2E) * (1.0f - Mk[idx]);
  } else {
    const int idx = (gb - 2048) * 256 + threadIdx.x;  // bh<<15 | j<<10 | g<<6 | d
    const int d  = idx & 63;
    const int g  = (idx >> 6) & 15;
    const int j  = (idx >> 10) & 31;
    const int bh = idx >> 15;
    const float* src = V + ((size_t)bh * S_LEN + j * 64 + g * 4) * DHEAD + d;
    float v0 = src[0], v1 = src[64], v2 = src[128], v3 = src[192];
    union { f16x2 h[2]; f16x4 v; } r;
    r.h[0] = h2f(pkh(v0, v1)); r.h[1] = h2f(pkh(v2, v3));
    *(f16x4*)(Vg + (size_t)idx * 4) = r.v;
  }
}

// ---------------------------------------------------------------- main ----
// 512 threads = 8 waves. Waves 0-3 (group 0): kv [0,1024); waves 4-7
// (group 1): kv [1024,2048). Each wave owns 2 q-strips (w4*16 and +64).
// Per group: double-buffered 64-kv K stream in LDS; V direct global->reg.
// LDS f16 map: K streams [0,16384), m at f16 16384; rest is padding that
// pins the allocator to the 2-blocks/CU (128-VGPR) budget.
__global__ __launch_bounds__(512)
__attribute__((amdgpu_waves_per_eu(4, 4)))
void attn_ws(
    const float* __restrict__ Q, const _Float16* __restrict__ Kswz,
    const _Float16* __restrict__ Vg, const float* __restrict__ madd_g,
    float* __restrict__ O) {
  __shared__ __align__(16) _Float16 smem[28672];   // 57344 B (pad: VGPR budget)

  const int tid  = threadIdx.x;       // 0..511
  const int lane = tid & 63;
  const int wave = tid >> 6;          // 0..7
  const int quad = lane >> 4;
  const int x    = lane & 15;
  const int g    = wave >> 2;         // kv half
  const int w4   = wave & 3;
  const int tidg = tid & 255;         // thread id within group

  // grid 512: 16 q-blocks (128 rows) x 32 bh; same-bh blocks share an XCD.
  const int blk  = blockIdx.x;
  const int bh   = (blk & 7) | (((blk >> 3) & 3) << 3);
  const int qblk = blk >> 5;          // 0..15
  const int b    = bh >> 4;

  const size_t base = (size_t)bh * S_LEN * DHEAD;
  const float*    Qb = Q + base;
  const _Float16* Kb = Kswz + base;
  const _Float16* Vb = Vg + base;
  const float*    Mb = madd_g + b * S_LEN;
  float* Ob = O + base;

  // integer LDS offsets (f16 units)
  const int koff = (g * 2) << 12;                              // + cur*4096
  float* const mbase = (float*)(smem + 16384) + (g * 2) * 64;  // + cur*64

  // Q fragments (B-operand of S^T = K Q^T) for two q-strips, pre-scaled.
  const int q0 = qblk * 128 + w4 * 16 + x;
  f16x8 qf[2][2];
#pragma unroll
  for (int u = 0; u < 2; ++u) {
    const float* qp = Qb + (size_t)(q0 + u * 64) * DHEAD + quad * 8;
#pragma unroll
    for (int kb = 0; kb < 2; ++kb) {
      float4 a = *(const float4*)(qp + kb * 32);
      float4 c = *(const float4*)(qp + kb * 32 + 4);
      union { f16x2 h[4]; f16x8 v; } r;
      r.h[0] = h2f(pkh(a.x * SCL2E, a.y * SCL2E));
      r.h[1] = h2f(pkh(a.z * SCL2E, a.w * SCL2E));
      r.h[2] = h2f(pkh(c.x * SCL2E, c.y * SCL2E));
      r.h[3] = h2f(pkh(c.z * SCL2E, c.w * SCL2E));
      qf[u][kb] = r.v;
    }
  }

  // prefetch one 64-kv K tile of this group's stream: 8KB + m 256B.
  auto prefetch = [&](int p, int bi) {
    const size_t off = (size_t)(g * NTILE + p) * 4096;
    const _Float16* ks = Kb + off + tidg * 8;
    _Float16* kd = smem + koff + bi * 4096 + tidg * 8;
    GLDS16(ks,        kd);
    GLDS16(ks + 2048, kd + 2048);
    if (tidg < 16)
      GLDS16(Mb + (g * NTILE + p) * 64 + tidg * 4, mbase + bi * 64 + tidg * 4);
  };

  // per-lane base for direct-global V granules (layout from prep's V image)
  const _Float16* vlane = Vb + 256 * quad + 4 * x;

  f32x4 xacc[2][4];
#pragma unroll
  for (int u = 0; u < 2; ++u)
#pragma unroll
    for (int m = 0; m < 4; ++m) xacc[u][m] = (f32x4){0.f, 0.f, 0.f, 0.f};
  float lsum[2] = {0.0f, 0.0f};
  const hf16x2 one2 = {(__fp16)1.0f, (__fp16)1.0f};

  prefetch(0, 0);
  __syncthreads();

  for (int p = 0; p < NTILE; ++p) {
    const int cur = p & 1;

    // V for this step: straight to registers, issued FIRST (oldest in the
    // vmem queue) so PV's wait leaves the K GLDS prefetch in flight.
    const _Float16* vp = vlane + (size_t)(g * NTILE + p) * 4096;
    f16x4 vf[4][4];
#pragma unroll
    for (int t = 0; t < 4; ++t)
#pragma unroll
      for (int m = 0; m < 4; ++m)
        vf[t][m] = *(const f16x4*)(vp + t * 1024 + m * 64);
    // pin issue order: V loads above, GLDS prefetch below
    __builtin_amdgcn_sched_barrier(0);

    if (p + 1 < NTILE) prefetch(p + 1, cur ^ 1);

    // S^T: A = K rows (rotated chunks), B = Q frags; K/mi shared by u=0,1.
    const _Float16* k0 = smem + koff + cur * 4096 + x * 64 + ((quad + x) & 7) * 8;
    const _Float16* k1 = smem + koff + cur * 4096 + x * 64 + ((quad + 4 + x) & 7) * 8;
    const float*    mp = mbase + cur * 64 + quad * 4;
    f16x4 pf[2][4];
#pragma unroll
    for (int t = 0; t < 4; ++t) {
      f16x8 ka0 = *(const f16x8*)(k0 + t * 1024);
      f16x8 ka1 = *(const f16x8*)(k1 + t * 1024);
      f32x4 mi = *(const f32x4*)(mp + t * 16);   // LDS broadcast read
#pragma unroll
      for (int u = 0; u < 2; ++u) {
        f32x4 st = __builtin_amdgcn_mfma_f32_16x16x32_f16(ka0, qf[u][0], mi, 0, 0, 0);
        st = __builtin_amdgcn_mfma_f32_16x16x32_f16(ka1, qf[u][1], st, 0, 0, 0);
        hf16x2 h0 = pkh(exp2_fast(st.x), exp2_fast(st.y));
        hf16x2 h1 = pkh(exp2_fast(st.z), exp2_fast(st.w));
#if __has_builtin(__builtin_amdgcn_fdot2)
        lsum[u] = __builtin_amdgcn_fdot2(h0, one2, lsum[u], false);
        lsum[u] = __builtin_amdgcn_fdot2(h1, one2, lsum[u], false);
#else
        f16x2 a0 = h2f(h0), a1 = h2f(h1);
        lsum[u] += (float)a0.x + (float)a0.y + (float)a1.x + (float)a1.y;
#endif
        union { f16x2 h[2]; f16x4 v; } r;
        r.h[0] = h2f(h0);
        r.h[1] = h2f(h1);
        pf[u][t] = r.v;
      }
    }
    // X^T += V^T P^T. V granules already in registers; serve both strips.
#pragma unroll
    for (int m = 0; m < 4; ++m) {
      f32x4 x0 = xacc[0][m];
      f32x4 x1 = xacc[1][m];
#pragma unroll
      for (int t = 0; t < 4; ++t) {
        x0 = __builtin_amdgcn_mfma_f32_16x16x16f16(vf[t][m], pf[0][t], x0, 0, 0, 0);
        x1 = __builtin_amdgcn_mfma_f32_16x16x16f16(vf[t][m], pf[1][t], x1, 0, 0, 0);
      }
      xacc[0][m] = x0;
      xacc[1][m] = x1;
    }
    __syncthreads();
  }

  // combine kv-halves: group 1 writes partials to LDS, group 0 reduces.
  // stride 36 floats keeps f32x4 alignment; one-shot epilogue cost.
  float* xls = (float*)smem;
  const int soff = (w4 * 64 + lane) * 36;
  if (g == 1) {
#pragma unroll
    for (int u = 0; u < 2; ++u) {
#pragma unroll
      for (int m = 0; m < 4; ++m)
        *(f32x4*)(xls + soff + (u * 4 + m) * 4) = xacc[u][m];
      xls[soff + 32 + u] = lsum[u];
    }
  }
  __syncthreads();
  if (g == 0) {
#pragma unroll
    for (int u = 0; u < 2; ++u) {
#pragma unroll
      for (int m = 0; m < 4; ++m) {
        f32x4 o = *(const f32x4*)(xls + soff + (u * 4 + m) * 4);
        xacc[u][m].x += o.x; xacc[u][m].y += o.y;
        xacc[u][m].z += o.z; xacc[u][m].w += o.w;
      }
      float l = lsum[u] + xls[soff + 32 + u];
      l += __shfl_xor(l, 16, 64);
      l += __shfl_xor(l, 32, 64);
      const float rl = 1.0f / l;
      float* op = Ob + (size_t)(q0 + u * 64) * DHEAD;
#pragma unroll
      for (int m = 0; m < 4; ++m) {
        float4 o;
        o.x = xacc[u][m].x * rl; o.y = xacc[u][m].y * rl;
        o.z = xacc[u][m].z * rl; o.w = xacc[u][m].w * rl;
        *(float4*)(op + m * 16 + quad * 4) = o;
      }
    }
  }
}

extern "C" void kernel_launch(void* const* d_in, const int* in_sizes, int n_in,
                              void* d_out, int out_size, void* d_ws, size_t ws_size,
                              hipStream_t stream) {
  const float* Q = (const float*)d_in[0];
  const float* K = (const float*)d_in[1];
  const float* V = (const float*)d_in[2];
  const float* M = (const float*)d_in[3];
  float* O = (float*)d_out;

  _Float16* Kswz = (_Float16*)d_ws;
  _Float16* Vg   = Kswz + 4194304;                       // +8 MB
  float*    madd = (float*)((char*)d_ws + 16777216);     // +16 MB
  hipLaunchKernelGGL(prep, dim3(6144), dim3(256), 0, stream, K, V, M, Kswz, Vg, madd);
  hipLaunchKernelGGL(attn_ws, dim3(512), dim3(512), 0, stream, Q, Kswz, Vg, madd, O);
}

// Round 10
// 142.298 us; speedup vs baseline: 1.0369x; 1.0328x over previous
//
#include <hip/hip_runtime.h>
#include <hip/hip_fp16.h>
#include <stdint.h>

// SoftmaxSelfAttention: B=2 H=16 S=2048 D=64, fp32 in/out.
// R14: R12's V-in-registers body in a 256-THREAD block. R13 post-mortem:
// LDS pad did nothing — VGPR stayed exactly 64, scratch exactly 36B/thread.
// Evidence: every 512-thr build got <=64 VGPRs (R7:52, R11:56, R12/13:64+
// spill); the 256-thr build (R6, launch_bounds(256,2)) got 88. The 64-cap is
// tied to 8-wave workgroups in this toolchain. So V-in-regs has never run
// unspilled. R14 geometry = R6's verified shape: 4 waves x 2 strips = 128
// q-rows, full kv sweep in 32x64kv steps, grid 512, no kv-split (no combine
// epilogue). LDS = K dbuf + m only, padded to 56KB (grid pins 2 blocks/CU
// anyway). Per step: [16 V reg-loads] -> sched_barrier -> [K/m GLDS
// prefetch] -> K ds_reads/QK/exp2 -> PV from regs -> barrier.

#define S_LEN   2048
#define DHEAD   64
#define NTILE   32                      // 64-kv tiles (full sweep)
#define CEXP    9.0f
#define SCL2E   0.18033688011112042f    // (1/sqrt(64)) * log2(e)
#define L2E     1.4426950408889634f

typedef __attribute__((ext_vector_type(4))) float    f32x4;
typedef __attribute__((ext_vector_type(2))) _Float16 f16x2;
typedef __attribute__((ext_vector_type(4))) _Float16 f16x4;
typedef __attribute__((ext_vector_type(8))) _Float16 f16x8;
typedef __attribute__((ext_vector_type(2))) __fp16   hf16x2;

static __device__ __forceinline__ float exp2_fast(float x) {
#if __has_builtin(__builtin_amdgcn_exp2f)
  return __builtin_amdgcn_exp2f(x);
#else
  float r;
  asm("v_exp_f32 %0, %1" : "=v"(r) : "v"(x));
  return r;
#endif
}

static __device__ __forceinline__ hf16x2 pkh(float a, float b) {
  return __builtin_amdgcn_cvt_pkrtz(a, b);
}
static __device__ __forceinline__ f16x2 h2f(hf16x2 h) {
  union { hf16x2 i; f16x2 o; } u; u.i = h; return u.o;
}

#define GLDS16(g, l)                                                  \
  __builtin_amdgcn_global_load_lds(                                   \
      (const __attribute__((address_space(1))) void*)(g),             \
      (__attribute__((address_space(3))) void*)(l), 16, 0, 0)

// ---------------------------------------------------------------- prep ----
// Blocks [0,2048): K image, chunk c (8 f16) of row kv at rotated pos
// (c+kv)&7; also madd_g[b][kv]. Blocks [2048,6144): V image, granule-major:
// granule (bh,j,g,d) = {V[64j+4g+i][d], i=0..3} at flat (bh<<15|j<<10|g<<6|d).
__global__ __launch_bounds__(256) void prep(
    const float* __restrict__ K, const float* __restrict__ V,
    const float* __restrict__ Mk, _Float16* __restrict__ Kswz,
    _Float16* __restrict__ Vg, float* __restrict__ madd_g) {
  const int gb = blockIdx.x;
  if (gb < 2048) {
    const int idx = gb * 256 + threadIdx.x;   // bh<<14 | kv<<3 | c
    const int c  = idx & 7;
    const int kv = (idx >> 3) & 2047;
    const int bh = idx >> 14;
    const float* src = K + ((size_t)bh * S_LEN + kv) * DHEAD + c * 8;
    float4 a = *(const float4*)(src);
    float4 d = *(const float4*)(src + 4);
    union { f16x2 h[4]; f16x8 v; } r;
    r.h[0] = h2f(pkh(a.x, a.y)); r.h[1] = h2f(pkh(a.z, a.w));
    r.h[2] = h2f(pkh(d.x, d.y)); r.h[3] = h2f(pkh(d.z, d.w));
    *(f16x8*)(Kswz + ((size_t)bh * S_LEN + kv) * DHEAD + ((c + kv) & 7) * 8) = r.v;
    if (idx < 2 * S_LEN)
      madd_g[idx] = -CEXP - (1.0e6f * L2E) * (1.0f - Mk[idx]);
  } else {
    const int idx = (gb - 2048) * 256 + threadIdx.x;  // bh<<15 | j<<10 | g<<6 | d
    const int d  = idx & 63;
    const int g  = (idx >> 6) & 15;
    const int j  = (idx >> 10) & 31;
    const int bh = idx >> 15;
    const float* src = V + ((size_t)bh * S_LEN + j * 64 + g * 4) * DHEAD + d;
    float v0 = src[0], v1 = src[64], v2 = src[128], v3 = src[192];
    union { f16x2 h[2]; f16x4 v; } r;
    r.h[0] = h2f(pkh(v0, v1)); r.h[1] = h2f(pkh(v2, v3));
    *(f16x4*)(Vg + (size_t)idx * 4) = r.v;
  }
}

// ---------------------------------------------------------------- main ----
// 256 threads = 4 waves; each wave owns 2 q-strips (wave*16 and +64) of a
// 128-row q-block. Full kv sweep, 32 steps of 64 kv. K double-buffered in
// LDS (GLDS); V + mask-bias handled per-wave: V direct global->reg issued
// first each step, mask staged with K.
__global__ __launch_bounds__(256, 2) void attn_ws(
    const float* __restrict__ Q, const _Float16* __restrict__ Kswz,
    const _Float16* __restrict__ Vg, const float* __restrict__ madd_g,
    float* __restrict__ O) {
  // K dbuf [0,8192) f16, m dbuf at f16 8192 (2x64 floats); padded to 56KB
  // so the 2-blocks/CU tier is unambiguous (grid gives 2/CU regardless).
  __shared__ __align__(16) _Float16 smem[28672];   // 57344 B

  const int tid  = threadIdx.x;       // 0..255
  const int lane = tid & 63;
  const int wave = tid >> 6;          // 0..3
  const int quad = lane >> 4;
  const int x    = lane & 15;

  // grid 512: 16 q-blocks (128 rows) x 32 bh; same-bh blocks share an XCD.
  const int blk  = blockIdx.x;
  const int bh   = (blk & 7) | (((blk >> 3) & 3) << 3);
  const int qblk = blk >> 5;          // 0..15
  const int b    = bh >> 4;

  const size_t base = (size_t)bh * S_LEN * DHEAD;
  const float*    Qb = Q + base;
  const _Float16* Kb = Kswz + base;
  const _Float16* Vb = Vg + base;
  const float*    Mb = madd_g + b * S_LEN;
  float* Ob = O + base;

  float* const mbase = (float*)(smem + 8192);      // + cur*64 floats

  // Q fragments (B-operand of S^T = K Q^T) for two q-strips, pre-scaled.
  const int q0 = qblk * 128 + wave * 16 + x;
  f16x8 qf[2][2];
#pragma unroll
  for (int u = 0; u < 2; ++u) {
    const float* qp = Qb + (size_t)(q0 + u * 64) * DHEAD + quad * 8;
#pragma unroll
    for (int kb = 0; kb < 2; ++kb) {
      float4 a = *(const float4*)(qp + kb * 32);
      float4 c = *(const float4*)(qp + kb * 32 + 4);
      union { f16x2 h[4]; f16x8 v; } r;
      r.h[0] = h2f(pkh(a.x * SCL2E, a.y * SCL2E));
      r.h[1] = h2f(pkh(a.z * SCL2E, a.w * SCL2E));
      r.h[2] = h2f(pkh(c.x * SCL2E, c.y * SCL2E));
      r.h[3] = h2f(pkh(c.z * SCL2E, c.w * SCL2E));
      qf[u][kb] = r.v;
    }
  }

  // prefetch one 64-kv K tile (8KB) + m (256B): 256 thr x 16B x 2 for K.
  auto prefetch = [&](int p, int bi) {
    const _Float16* ks = Kb + (size_t)p * 4096 + tid * 8;
    _Float16* kd = smem + bi * 4096 + tid * 8;
    GLDS16(ks,        kd);
    GLDS16(ks + 2048, kd + 2048);
    if (tid < 16)
      GLDS16(Mb + p * 64 + tid * 4, mbase + bi * 64 + tid * 4);
  };

  // per-lane base for direct-global V granules (layout from prep's V image)
  const _Float16* vlane = Vb + 256 * quad + 4 * x;

  f32x4 xacc[2][4];
#pragma unroll
  for (int u = 0; u < 2; ++u)
#pragma unroll
    for (int m = 0; m < 4; ++m) xacc[u][m] = (f32x4){0.f, 0.f, 0.f, 0.f};
  float lsum[2] = {0.0f, 0.0f};
  const hf16x2 one2 = {(__fp16)1.0f, (__fp16)1.0f};

  prefetch(0, 0);
  __syncthreads();

  for (int p = 0; p < NTILE; ++p) {
    const int cur = p & 1;

    // V for this step: straight to registers, issued FIRST (oldest in the
    // vmem queue) so PV's wait leaves the K GLDS prefetch in flight.
    const _Float16* vp = vlane + (size_t)p * 4096;
    f16x4 vf[4][4];
#pragma unroll
    for (int t = 0; t < 4; ++t)
#pragma unroll
      for (int m = 0; m < 4; ++m)
        vf[t][m] = *(const f16x4*)(vp + t * 1024 + m * 64);
    // pin issue order: V loads above, GLDS prefetch below
    __builtin_amdgcn_sched_barrier(0);

    if (p + 1 < NTILE) prefetch(p + 1, cur ^ 1);

    // S^T: A = K rows (rotated chunks), B = Q frags; K/mi shared by u=0,1.
    const _Float16* k0 = smem + cur * 4096 + x * 64 + ((quad + x) & 7) * 8;
    const _Float16* k1 = smem + cur * 4096 + x * 64 + ((quad + 4 + x) & 7) * 8;
    const float*    mp = mbase + cur * 64 + quad * 4;
    f16x4 pf[2][4];
#pragma unroll
    for (int t = 0; t < 4; ++t) {
      f16x8 ka0 = *(const f16x8*)(k0 + t * 1024);
      f16x8 ka1 = *(const f16x8*)(k1 + t * 1024);
      f32x4 mi = *(const f32x4*)(mp + t * 16);   // LDS broadcast read
#pragma unroll
      for (int u = 0; u < 2; ++u) {
        f32x4 st = __builtin_amdgcn_mfma_f32_16x16x32_f16(ka0, qf[u][0], mi, 0, 0, 0);
        st = __builtin_amdgcn_mfma_f32_16x16x32_f16(ka1, qf[u][1], st, 0, 0, 0);
        hf16x2 h0 = pkh(exp2_fast(st.x), exp2_fast(st.y));
        hf16x2 h1 = pkh(exp2_fast(st.z), exp2_fast(st.w));
#if __has_builtin(__builtin_amdgcn_fdot2)
        lsum[u] = __builtin_amdgcn_fdot2(h0, one2, lsum[u], false);
        lsum[u] = __builtin_amdgcn_fdot2(h1, one2, lsum[u], false);
#else
        f16x2 a0 = h2f(h0), a1 = h2f(h1);
        lsum[u] += (float)a0.x + (float)a0.y + (float)a1.x + (float)a1.y;
#endif
        union { f16x2 h[2]; f16x4 v; } r;
        r.h[0] = h2f(h0);
        r.h[1] = h2f(h1);
        pf[u][t] = r.v;
      }
    }
    // X^T += V^T P^T. V granules already in registers; serve both strips.
#pragma unroll
    for (int m = 0; m < 4; ++m) {
      f32x4 x0 = xacc[0][m];
      f32x4 x1 = xacc[1][m];
#pragma unroll
      for (int t = 0; t < 4; ++t) {
        x0 = __builtin_amdgcn_mfma_f32_16x16x16f16(vf[t][m], pf[0][t], x0, 0, 0, 0);
        x1 = __builtin_amdgcn_mfma_f32_16x16x16f16(vf[t][m], pf[1][t], x1, 0, 0, 0);
      }
      xacc[0][m] = x0;
      xacc[1][m] = x1;
    }
    __syncthreads();
  }

  // epilogue: reduce l across quads (same q = x), normalize, store.
#pragma unroll
  for (int u = 0; u < 2; ++u) {
    float l = lsum[u];
    l += __shfl_xor(l, 16, 64);
    l += __shfl_xor(l, 32, 64);
    const float rl = 1.0f / l;
    float* op = Ob + (size_t)(q0 + u * 64) * DHEAD;
#pragma unroll
    for (int m = 0; m < 4; ++m) {
      float4 o;
      o.x = xacc[u][m].x * rl; o.y = xacc[u][m].y * rl;
      o.z = xacc[u][m].z * rl; o.w = xacc[u][m].w * rl;
      *(float4*)(op + m * 16 + quad * 4) = o;
    }
  }
}

extern "C" void kernel_launch(void* const* d_in, const int* in_sizes, int n_in,
                              void* d_out, int out_size, void* d_ws, size_t ws_size,
                              hipStream_t stream) {
  const float* Q = (const float*)d_in[0];
  const float* K = (const float*)d_in[1];
  const float* V = (const float*)d_in[2];
  const float* M = (const float*)d_in[3];
  float* O = (float*)d_out;

  _Float16* Kswz = (_Float16*)d_ws;
  _Float16* Vg   = Kswz + 4194304;                       // +8 MB
  float*    madd = (float*)((char*)d_ws + 16777216);     // +16 MB
  hipLaunchKernelGGL(prep, dim3(6144), dim3(256), 0, stream, K, V, M, Kswz, Vg, madd);
  hipLaunchKernelGGL(attn_ws, dim3(512), dim3(256), 0, stream, Q, Kswz, Vg, madd, O);
}